// Round 2
// baseline (13781.676 us; speedup 1.0000x reference)
//
#include <hip/hip_runtime.h>
#include <stdint.h>

// Problem dims (fixed)
#define B_  256
#define T_  1024
#define D_  128
#define H_  512
#define G4_ 2048            // 4*H
#define BT_ (B_ * T_)

// Persistent-LSTM partitioning
#define GRP_    8           // batch groups (32 rows each)
#define WPG_    8           // workgroups per group (64 hidden cols each)
#define CNTSTR_ 16          // u32 stride per counter (64B line)

typedef unsigned short u16;
typedef __attribute__((ext_vector_type(8))) short  bf16x8;  // 8 bf16 in 4 VGPRs
typedef __attribute__((ext_vector_type(8))) u16    u16x8;
typedef __attribute__((ext_vector_type(4))) float  f32x4;

static __device__ __forceinline__ u16 f2bf(float f) {
  uint32_t u = __builtin_bit_cast(uint32_t, f);
  u += 0x7FFFu + ((u >> 16) & 1u);   // RNE
  return (u16)(u >> 16);
}

static __device__ __forceinline__ u16x8 pack8(float4 a, float4 b) {
  u16x8 p;
  p[0] = f2bf(a.x); p[1] = f2bf(a.y); p[2] = f2bf(a.z); p[3] = f2bf(a.w);
  p[4] = f2bf(b.x); p[5] = f2bf(b.y); p[6] = f2bf(b.z); p[7] = f2bf(b.w);
  return p;
}

static __device__ __forceinline__ float fast_sig(float x) {
  return 1.f / (1.f + __expf(-x));
}
static __device__ __forceinline__ float fast_tanh(float x) {
  return 1.f - 2.f / (__expf(2.f * x) + 1.f);
}

// ---------------------------------------------------------------------------
// prep: bf16 weight copies, bias sum, zero counters and out[:,0,:]
// ---------------------------------------------------------------------------
__global__ void prep_kernel(const float* __restrict__ Whh, const float* __restrict__ Wih,
                            const float* __restrict__ w1,  const float* __restrict__ w2,
                            const float* __restrict__ b_ih, const float* __restrict__ b_hh,
                            u16* __restrict__ Whh_bf, u16* __restrict__ Wih_bf,
                            u16* __restrict__ w1y_bf, u16* __restrict__ w2_bf,
                            float* __restrict__ w1s, float* __restrict__ bsum,
                            uint32_t* __restrict__ cnt, float* __restrict__ Yd) {
  const int idx = blockIdx.x * blockDim.x + threadIdx.x;
  if (idx < G4_ * H_) Whh_bf[idx] = f2bf(Whh[idx]);          // 1,048,576
  if (idx < G4_ * D_) Wih_bf[idx] = f2bf(Wih[idx]);          // 262,144
  if (idx < H_ * H_) {                                       // 262,144
    const int n = idx >> 9, k = idx & 511;
    w1y_bf[idx] = f2bf(w1[n * 513 + 1 + k]);                 // w1[:,1:]
    w2_bf[idx]  = f2bf(w2[idx]);
  }
  if (idx < H_)  w1s[idx]  = w1[idx * 513];                  // w1[:,0]
  if (idx < G4_) bsum[idx] = b_ih[idx] + b_hh[idx];
  if (idx < T_ * GRP_ * CNTSTR_) cnt[idx] = 0;               // 131,072
  if (idx < B_ * H_) {                                       // 131,072
    const int b = idx >> 9, h = idx & 511;
    Yd[(size_t)b * T_ * H_ + h] = 0.f;                       // out[b,0,:] = h_0 = 0
  }
}

// ---------------------------------------------------------------------------
// Phase 1: persistent LSTM. Grid = 64 WGs x 1024 thr (16 waves).
// WG (g, w2): batch rows [g*32, g*32+32), hidden cols [w2*64, w2*64+64).
// Wave wv: gate gw = wv&3, hidden block hb = wv>>2 (16 cols).
// Weights held in VGPRs (20 bf16x8 frags/lane); c-state in 2 regs/thread.
// h history lives in Yd (=d_out); h writes are agent-scope atomics (MALL
// write-through) so cross-XCD consumers' fresh-address cached reads are safe.
// Per-step sync: per-(group,step) arrive counter, release-add / acquire-spin.
// ---------------------------------------------------------------------------
__launch_bounds__(1024, 4)
__global__ void lstm_persist_kernel(const float* __restrict__ x,
                                    const u16* __restrict__ Whh_bf,
                                    const u16* __restrict__ Wih_bf,
                                    const float* __restrict__ bsum,
                                    float* __restrict__ Yd,
                                    uint32_t* __restrict__ cnt) {
  __shared__ u16   As[32][648];       // 32 x 640 bf16 A-tile (pad: +4 banks/row)
  __shared__ float Gs[4][32][66];     // gate exchange

  const int tid  = threadIdx.x;
  const int lane = tid & 63;
  const int wv   = tid >> 6;          // 0..15
  const int gw   = wv & 3;            // gate (i,f,g,o)
  const int hb   = wv >> 2;           // hidden block 0..3
  const int g    = blockIdx.x >> 3;   // batch group
  const int w2   = blockIdx.x & 7;    // col group
  const int br0  = g * 32;
  const int hc0  = w2 * 64;

  // ---- persistent weight fragments (80 VGPR/lane) ----
  bf16x8 wfrag[20];
  {
    const int j  = gw * H_ + hc0 + hb * 16 + (lane & 15);
    const int ko = (lane >> 4) * 8;
#pragma unroll
    for (int kt = 0; kt < 16; ++kt)
      wfrag[kt] = *(const bf16x8*)(Whh_bf + (size_t)j * H_ + kt * 32 + ko);
#pragma unroll
    for (int kt = 0; kt < 4; ++kt)
      wfrag[16 + kt] = *(const bf16x8*)(Wih_bf + (size_t)j * D_ + kt * 32 + ko);
  }

  // ---- per-thread cell state: row er, cols (hcg, hcg+1) ----
  const int er  = tid >> 5;           // 0..31
  const int ec  = (tid & 31) * 2;     // 0..62 (even)
  const int hcg = hc0 + ec;
  float c0 = 0.f, c1 = 0.f;
  const float bi0 = bsum[hcg],            bi1 = bsum[hcg + 1];
  const float bf0 = bsum[H_ + hcg],       bf1 = bsum[H_ + hcg + 1];
  const float bg0 = bsum[2 * H_ + hcg],   bg1 = bsum[2 * H_ + hcg + 1];
  const float bo0 = bsum[3 * H_ + hcg],   bo1 = bsum[3 * H_ + hcg + 1];

  const int sr = tid & 31;            // staging row
  const int sk = tid >> 5;            // staging chunk 0..31

  for (int s = 0; s < T_ - 1; ++s) {
    // ---- stage x-part (cols 512..639) — independent of h_s, overlaps spin ----
    if (tid < 512) {
      const float4* x4 = (const float4*)(x + ((size_t)(br0 + sr) * T_ + s) * D_);
      float4 a = x4[2 * sk], b = x4[2 * sk + 1];
      *(u16x8*)&As[sr][(sk + 64) * 8] = pack8(a, b);
    }
    // ---- wait for h_s ----
    if (s > 0 && tid == 0) {
      uint32_t* cp = cnt + (size_t)(s * GRP_ + g) * CNTSTR_;
      while (__hip_atomic_load(cp, __ATOMIC_ACQUIRE, __HIP_MEMORY_SCOPE_AGENT) < WPG_)
        __builtin_amdgcn_s_sleep(1);
    }
    __syncthreads();

    // ---- stage h-part (cols 0..511) fp32 -> bf16 ----
    {
      const float4* h4 = (const float4*)(Yd + ((size_t)(br0 + sr) * T_ + s) * H_);
      float4 a = h4[2 * sk], b = h4[2 * sk + 1];
      *(u16x8*)&As[sr][sk * 8] = pack8(a, b);
      a = h4[2 * (sk + 32)]; b = h4[2 * (sk + 32) + 1];
      *(u16x8*)&As[sr][(sk + 32) * 8] = pack8(a, b);
    }
    __syncthreads();

    // ---- MFMA: 2 M-tiles x 1 N-tile x K=640 ----
    f32x4 acc0 = {}, acc1 = {};
    {
      const int ar = lane & 15;
      const int ko = (lane >> 4) * 8;
#pragma unroll
      for (int kt = 0; kt < 20; ++kt) {
        bf16x8 a0 = *(const bf16x8*)&As[ar][kt * 32 + ko];
        bf16x8 a1 = *(const bf16x8*)&As[16 + ar][kt * 32 + ko];
        acc0 = __builtin_amdgcn_mfma_f32_16x16x32_bf16(a0, wfrag[kt], acc0, 0, 0, 0);
        acc1 = __builtin_amdgcn_mfma_f32_16x16x32_bf16(a1, wfrag[kt], acc1, 0, 0, 0);
      }
    }

    // ---- gate exchange ----
    {
      const int gc = hb * 16 + (lane & 15);
      const int rr = (lane >> 4) * 4;
#pragma unroll
      for (int r = 0; r < 4; ++r) {
        Gs[gw][rr + r][gc]      = acc0[r];
        Gs[gw][16 + rr + r][gc] = acc1[r];
      }
    }
    __syncthreads();

    // ---- cell update + device-visible h store ----
    {
      const float gi0 = Gs[0][er][ec] + bi0, gi1 = Gs[0][er][ec + 1] + bi1;
      const float gf0 = Gs[1][er][ec] + bf0, gf1 = Gs[1][er][ec + 1] + bf1;
      const float gg0 = Gs[2][er][ec] + bg0, gg1 = Gs[2][er][ec + 1] + bg1;
      const float go0 = Gs[3][er][ec] + bo0, go1 = Gs[3][er][ec + 1] + bo1;
      c0 = fast_sig(gf0) * c0 + fast_sig(gi0) * fast_tanh(gg0);
      c1 = fast_sig(gf1) * c1 + fast_sig(gi1) * fast_tanh(gg1);
      const float h0 = fast_sig(go0) * fast_tanh(c0);
      const float h1 = fast_sig(go1) * fast_tanh(c1);
      const uint64_t hv = ((uint64_t)__builtin_bit_cast(uint32_t, h1) << 32)
                        |  (uint64_t)__builtin_bit_cast(uint32_t, h0);
      __hip_atomic_store((uint64_t*)(Yd + ((size_t)(br0 + er) * T_ + (s + 1)) * H_ + hcg),
                         hv, __ATOMIC_RELAXED, __HIP_MEMORY_SCOPE_AGENT);
    }
    __syncthreads();   // drains all threads' stores (vmcnt 0) before arrive

    if (tid == 0)
      __hip_atomic_fetch_add(cnt + (size_t)((s + 1) * GRP_ + g) * CNTSTR_, 1u,
                             __ATOMIC_RELEASE, __HIP_MEMORY_SCOPE_AGENT);
  }
}

// ---------------------------------------------------------------------------
// Phase 2: GEMM (M=BT, N=512, K=512), 128x128 tile, BK=64, 4 waves (2x2).
// MODE 0: A = Y fp32 (d_out); epi: Abf = bf16(tanh(acc + b1 + s*w1s))
// MODE 1: A = Abf bf16;       epi: Yd += dt * t[row] * (acc + b2)
// ---------------------------------------------------------------------------
template <int MODE>
__launch_bounds__(256)
__global__ void ode_gemm(const void* __restrict__ Asrc,
                         const u16* __restrict__ Wbf,
                         const float* __restrict__ bias,
                         const float* __restrict__ aux,   // MODE0: w1s ; MODE1: t (BT)
                         float* __restrict__ Yd,
                         u16* __restrict__ Abf_out,
                         float sval) {                    // MODE0: s ; MODE1: dt
  __shared__ u16 As[128][72];
  __shared__ u16 Bs[128][72];

  const int tid  = threadIdx.x;
  const int lane = tid & 63;
  const int wid  = tid >> 6;
  const int wm   = wid >> 1, wn = wid & 1;
  const int n0   = blockIdx.x * 128;
  const size_t m0 = (size_t)blockIdx.y * 128;

  f32x4 acc[4][4] = {};

  const int srow = tid >> 1;           // 0..127
  const int sc0  = (tid & 1) * 32;     // 0 / 32

  for (int kc = 0; kc < 8; ++kc) {
    const int k0 = kc * 64;
    if (MODE == 0) {
      const float4* s4 = (const float4*)((const float*)Asrc + (m0 + srow) * 512 + k0 + sc0);
      for (int u = 0; u < 4; ++u) {
        float4 fa = s4[2 * u], fb = s4[2 * u + 1];
        *(u16x8*)&As[srow][sc0 + u * 8] = pack8(fa, fb);
      }
    } else {
      const u16* s = (const u16*)Asrc + (m0 + srow) * 512 + k0 + sc0;
      for (int u = 0; u < 4; ++u)
        *(u16x8*)&As[srow][sc0 + u * 8] = *(const u16x8*)(s + u * 8);
    }
    {
      const u16* s = Wbf + (size_t)(n0 + srow) * 512 + k0 + sc0;
      for (int u = 0; u < 4; ++u)
        *(u16x8*)&Bs[srow][sc0 + u * 8] = *(const u16x8*)(s + u * 8);
    }
    __syncthreads();

    for (int ks = 0; ks < 2; ++ks) {
      const int kl = ks * 32 + ((lane >> 4) << 3);
      bf16x8 af[4], bfv[4];
      for (int mt = 0; mt < 4; ++mt)
        af[mt] = *(const bf16x8*)&As[wm * 64 + mt * 16 + (lane & 15)][kl];
      for (int nt = 0; nt < 4; ++nt)
        bfv[nt] = *(const bf16x8*)&Bs[wn * 64 + nt * 16 + (lane & 15)][kl];
      for (int mt = 0; mt < 4; ++mt)
        for (int nt = 0; nt < 4; ++nt)
          acc[mt][nt] = __builtin_amdgcn_mfma_f32_16x16x32_bf16(af[mt], bfv[nt], acc[mt][nt], 0, 0, 0);
    }
    __syncthreads();
  }

  for (int mt = 0; mt < 4; ++mt) {
    for (int nt = 0; nt < 4; ++nt) {
      const int coll = wn * 64 + nt * 16 + (lane & 15);
      const int colg = n0 + coll;
      const float bv = bias[colg];
      const float extra = (MODE == 0) ? sval * aux[colg] : 0.f;
      for (int r = 0; r < 4; ++r) {
        const int rowl = wm * 64 + mt * 16 + ((lane >> 4) << 2) + r;
        const size_t rowg = m0 + rowl;
        const float gv = acc[mt][nt][r] + bv + extra;
        if (MODE == 0) {
          Abf_out[rowg * 512 + colg] = f2bf(fast_tanh(gv));
        } else {
          const float tt = aux[rowg];
          Yd[rowg * 512 + colg] = fmaf(sval * tt, gv, Yd[rowg * 512 + colg]);
        }
      }
    }
  }
}

// ---------------------------------------------------------------------------
extern "C" void kernel_launch(void* const* d_in, const int* in_sizes, int n_in,
                              void* d_out, int out_size, void* d_ws, size_t ws_size,
                              hipStream_t stream) {
  const float* x    = (const float*)d_in[0];
  const float* t    = (const float*)d_in[1];
  const float* W_ih = (const float*)d_in[2];
  const float* W_hh = (const float*)d_in[3];
  const float* b_ih = (const float*)d_in[4];
  const float* b_hh = (const float*)d_in[5];
  const float* w1   = (const float*)d_in[6];
  const float* b1   = (const float*)d_in[7];
  const float* w2   = (const float*)d_in[8];
  const float* b2   = (const float*)d_in[9];
  float* Yd = (float*)d_out;   // (B,T,H) fp32; h history and ODE state

  char* ws = (char*)d_ws;
  size_t off = 0;
  auto alloc = [&](size_t bytes) {
    void* p = ws + off;
    off += (bytes + 255) & ~(size_t)255;
    return p;
  };
  u16*      Whh_bf = (u16*)alloc((size_t)G4_ * H_ * 2);          //   2 MB
  u16*      Wih_bf = (u16*)alloc((size_t)G4_ * D_ * 2);          // 512 KB
  u16*      w1y_bf = (u16*)alloc((size_t)H_ * H_ * 2);           // 512 KB
  u16*      w2_bf  = (u16*)alloc((size_t)H_ * H_ * 2);           // 512 KB
  float*    w1s    = (float*)alloc(H_ * 4);
  float*    bsum   = (float*)alloc(G4_ * 4);
  uint32_t* cnt    = (uint32_t*)alloc((size_t)T_ * GRP_ * CNTSTR_ * 4); // 512 KB
  u16*      Abf    = (u16*)alloc((size_t)BT_ * H_ * 2);          // 256 MB

  prep_kernel<<<4096, 256, 0, stream>>>(W_hh, W_ih, w1, w2, b_ih, b_hh,
                                        Whh_bf, Wih_bf, w1y_bf, w2_bf, w1s, bsum, cnt, Yd);

  // Phase 1: persistent LSTM (64 WGs, always co-resident on 256 CUs)
  lstm_persist_kernel<<<dim3(GRP_ * WPG_), 1024, 0, stream>>>(x, Whh_bf, Wih_bf, bsum, Yd, cnt);

  // Phase 2: 4 Euler steps, each = two fused GEMMs over all B*T rows
  for (int k = 0; k < 4; ++k) {
    ode_gemm<0><<<dim3(4, 2048), 256, 0, stream>>>(Yd, w1y_bf, b1, w1s, nullptr, Abf, 0.25f * k);
    ode_gemm<1><<<dim3(4, 2048), 256, 0, stream>>>(Abf, w2_bf, b2, t, Yd, nullptr, 0.25f);
  }
}

// Round 3
// 13117.560 us; speedup vs baseline: 1.0506x; 1.0506x over previous
//
#include <hip/hip_runtime.h>
#include <stdint.h>

// Problem dims (fixed)
#define B_  256
#define T_  1024
#define D_  128
#define H_  512
#define G4_ 2048            // 4*H
#define BT_ (B_ * T_)

// Persistent-LSTM partitioning
#define GRP_    8           // batch groups (32 rows each)
#define WPG_    8           // workgroups per group (64 hidden cols each)

typedef unsigned short u16;
typedef __attribute__((ext_vector_type(8))) short  bf16x8;  // 8 bf16 in 4 VGPRs
typedef __attribute__((ext_vector_type(8))) u16    u16x8;
typedef __attribute__((ext_vector_type(4))) float  f32x4;

static __device__ __forceinline__ u16 f2bf(float f) {
  uint32_t u = __builtin_bit_cast(uint32_t, f);
  u += 0x7FFFu + ((u >> 16) & 1u);   // RNE
  return (u16)(u >> 16);
}

static __device__ __forceinline__ u16x8 pack8(float4 a, float4 b) {
  u16x8 p;
  p[0] = f2bf(a.x); p[1] = f2bf(a.y); p[2] = f2bf(a.z); p[3] = f2bf(a.w);
  p[4] = f2bf(b.x); p[5] = f2bf(b.y); p[6] = f2bf(b.z); p[7] = f2bf(b.w);
  return p;
}

static __device__ __forceinline__ float fast_sig(float x) {
  return 1.f / (1.f + __expf(-x));
}
static __device__ __forceinline__ float fast_tanh(float x) {
  return 1.f - 2.f / (__expf(2.f * x) + 1.f);
}

// ---------------------------------------------------------------------------
// prep: bf16 weight copies, bias sum, zero exchange buffer and out[:,0,:]
// ---------------------------------------------------------------------------
__global__ void prep_kernel(const float* __restrict__ Whh, const float* __restrict__ Wih,
                            const float* __restrict__ w1,  const float* __restrict__ w2,
                            const float* __restrict__ b_ih, const float* __restrict__ b_hh,
                            u16* __restrict__ Whh_bf, u16* __restrict__ Wih_bf,
                            u16* __restrict__ w1y_bf, u16* __restrict__ w2_bf,
                            float* __restrict__ w1s, float* __restrict__ bsum,
                            uint32_t* __restrict__ xch, float* __restrict__ Yd) {
  const int idx = blockIdx.x * blockDim.x + threadIdx.x;
  if (idx < G4_ * H_) Whh_bf[idx] = f2bf(Whh[idx]);          // 1,048,576
  if (idx < G4_ * D_) Wih_bf[idx] = f2bf(Wih[idx]);          // 262,144
  if (idx < H_ * H_) {                                       // 262,144
    const int n = idx >> 9, k = idx & 511;
    w1y_bf[idx] = f2bf(w1[n * 513 + 1 + k]);                 // w1[:,1:]
    w2_bf[idx]  = f2bf(w2[idx]);
  }
  if (idx < H_)  w1s[idx]  = w1[idx * 513];                  // w1[:,0]
  if (idx < G4_) bsum[idx] = b_ih[idx] + b_hh[idx];
  if (idx < 2 * B_ * H_) xch[idx] = 0;                       // 262,144 (tag 0)
  if (idx < B_ * H_) {                                       // 131,072
    const int b = idx >> 9, h = idx & 511;
    Yd[(size_t)b * T_ * H_ + h] = 0.f;                       // out[b,0,:] = h_0 = 0
  }
}

// ---------------------------------------------------------------------------
// Phase 1: persistent LSTM. Grid = 64 WGs x 1024 thr (16 waves).
// WG (g, j): batch rows [g*32, g*32+32), hidden cols [j*64, j*64+64).
// Weights in VGPRs (20 bf16x8 frags/lane); c-state in 2 regs/thread.
//
// Cross-WG h exchange: self-validating tagged words. Producer packs
// (bf16(h) << 16) | step_tag into a u32; pairs stored as one relaxed
// agent-scope u64 atomic (write-through to MALL). Consumers poll their own
// words with relaxed agent-scope u64 atomic loads (MALL-coherent, no L2
// invalidation) until the tag matches, then feed the bf16 payload straight
// into LDS. Double-buffered by step parity: a WG reaches the store that
// overwrites parity p only after observing all tags of the following step,
// which requires every group member to have finished reading p. Tags are
// 1..1023; prep zeroes the buffer each call (replay-safe).
// ---------------------------------------------------------------------------
__launch_bounds__(1024, 4)
__global__ void lstm_persist_kernel(const float* __restrict__ x,
                                    const u16* __restrict__ Whh_bf,
                                    const u16* __restrict__ Wih_bf,
                                    const float* __restrict__ bsum,
                                    float* __restrict__ Yd,
                                    uint32_t* __restrict__ xch) {
  __shared__ u16   As[32][648];       // 32 x 640 bf16 A-tile
  __shared__ float Gs[4][32][66];     // gate exchange

  const int tid  = threadIdx.x;
  const int lane = tid & 63;
  const int wv   = tid >> 6;          // 0..15
  const int gw   = wv & 3;            // gate (i,f,g,o)
  const int hb   = wv >> 2;           // hidden block 0..3
  const int g    = blockIdx.x >> 3;   // batch group
  const int j    = blockIdx.x & 7;    // col group
  const int br0  = g * 32;
  const int hc0  = j * 64;

  // ---- persistent weight fragments (80 VGPR/lane) ----
  bf16x8 wfrag[20];
  {
    const int jj = gw * H_ + hc0 + hb * 16 + (lane & 15);
    const int ko = (lane >> 4) * 8;
#pragma unroll
    for (int kt = 0; kt < 16; ++kt)
      wfrag[kt] = *(const bf16x8*)(Whh_bf + (size_t)jj * H_ + kt * 32 + ko);
#pragma unroll
    for (int kt = 0; kt < 4; ++kt)
      wfrag[16 + kt] = *(const bf16x8*)(Wih_bf + (size_t)jj * D_ + kt * 32 + ko);
  }

  // ---- per-thread cell state: row er, cols (hcg, hcg+1) ----
  const int er  = tid >> 5;           // 0..31
  const int ec  = (tid & 31) * 2;     // 0..62 (even)
  const int hcg = hc0 + ec;
  float c0 = 0.f, c1 = 0.f;
  const float bi0 = bsum[hcg],            bi1 = bsum[hcg + 1];
  const float bf0 = bsum[H_ + hcg],       bf1 = bsum[H_ + hcg + 1];
  const float bg0 = bsum[2 * H_ + hcg],   bg1 = bsum[2 * H_ + hcg + 1];
  const float bo0 = bsum[3 * H_ + hcg],   bo1 = bsum[3 * H_ + hcg + 1];

  // staging maps
  const int sr = tid & 31;            // x-stage row
  const int sk = tid >> 5;            // x-stage chunk
  const int pr = tid >> 5;            // poll row 0..31
  const int cb = tid & 31;            // poll col-block (16 u32 cols each)

  for (int s = 0; s < T_ - 1; ++s) {
    // ---- stage x-part (cols 512..639) — independent of h_s ----
    if (tid < 512) {
      const float4* x4 = (const float4*)(x + ((size_t)(br0 + sr) * T_ + s) * D_);
      float4 a = x4[2 * sk], b = x4[2 * sk + 1];
      *(u16x8*)&As[sr][(sk + 64) * 8] = pack8(a, b);
    }

    // ---- stage h-part (cols 0..511): poll tagged exchange words ----
    if (s == 0) {
      u16x8 z = {};
      *(u16x8*)&As[pr][cb * 16]     = z;
      *(u16x8*)&As[pr][cb * 16 + 8] = z;
    } else {
      const uint64_t* src = (const uint64_t*)
        (xch + (((size_t)(s & 1) * B_ + br0 + pr) << 9) + cb * 16);
      const uint32_t want = (uint32_t)s;
      uint64_t v[8];
      bool all_ok;
      do {
        all_ok = true;
#pragma unroll
        for (int i = 0; i < 8; ++i)
          v[i] = __hip_atomic_load(src + i, __ATOMIC_RELAXED, __HIP_MEMORY_SCOPE_AGENT);
#pragma unroll
        for (int i = 0; i < 8; ++i) {
          all_ok = all_ok && (((uint32_t)v[i] & 0xFFFFu) == want) &&
                             (((uint32_t)(v[i] >> 32) & 0xFFFFu) == want);
        }
      } while (!all_ok);
      u16x8 a0, a1;
#pragma unroll
      for (int i = 0; i < 4; ++i) {
        a0[2 * i]     = (u16)(v[i] >> 16);
        a0[2 * i + 1] = (u16)(v[i] >> 48);
        a1[2 * i]     = (u16)(v[4 + i] >> 16);
        a1[2 * i + 1] = (u16)(v[4 + i] >> 48);
      }
      *(u16x8*)&As[pr][cb * 16]     = a0;
      *(u16x8*)&As[pr][cb * 16 + 8] = a1;
    }
    __syncthreads();

    // ---- MFMA: 2 M-tiles x 1 N-tile x K=640 ----
    f32x4 acc0 = {}, acc1 = {};
    {
      const int ar = lane & 15;
      const int ko = (lane >> 4) * 8;
#pragma unroll
      for (int kt = 0; kt < 20; ++kt) {
        bf16x8 a0 = *(const bf16x8*)&As[ar][kt * 32 + ko];
        bf16x8 a1 = *(const bf16x8*)&As[16 + ar][kt * 32 + ko];
        acc0 = __builtin_amdgcn_mfma_f32_16x16x32_bf16(a0, wfrag[kt], acc0, 0, 0, 0);
        acc1 = __builtin_amdgcn_mfma_f32_16x16x32_bf16(a1, wfrag[kt], acc1, 0, 0, 0);
      }
    }

    // ---- gate exchange ----
    {
      const int gc = hb * 16 + (lane & 15);
      const int rr = (lane >> 4) * 4;
#pragma unroll
      for (int r = 0; r < 4; ++r) {
        Gs[gw][rr + r][gc]      = acc0[r];
        Gs[gw][16 + rr + r][gc] = acc1[r];
      }
    }
    __syncthreads();

    // ---- cell update + h publication ----
    {
      const float gi0 = Gs[0][er][ec] + bi0, gi1 = Gs[0][er][ec + 1] + bi1;
      const float gf0 = Gs[1][er][ec] + bf0, gf1 = Gs[1][er][ec + 1] + bf1;
      const float gg0 = Gs[2][er][ec] + bg0, gg1 = Gs[2][er][ec + 1] + bg1;
      const float go0 = Gs[3][er][ec] + bo0, go1 = Gs[3][er][ec + 1] + bo1;
      c0 = fast_sig(gf0) * c0 + fast_sig(gi0) * fast_tanh(gg0);
      c1 = fast_sig(gf1) * c1 + fast_sig(gi1) * fast_tanh(gg1);
      const float h0 = fast_sig(go0) * fast_tanh(c0);
      const float h1 = fast_sig(go1) * fast_tanh(c1);
      const uint32_t tag = (uint32_t)(s + 1);
      const uint32_t lo  = ((uint32_t)f2bf(h0) << 16) | tag;
      const uint32_t hi  = ((uint32_t)f2bf(h1) << 16) | tag;
      // tagged bf16 exchange word first (consumers wait on it) ...
      __hip_atomic_store((uint64_t*)(xch + (((size_t)((s + 1) & 1) * B_ + br0 + er) << 9) + hcg),
                         ((uint64_t)hi << 32) | lo,
                         __ATOMIC_RELAXED, __HIP_MEMORY_SCOPE_AGENT);
      // ... then the fp32 history for phase 2 / output
      float2 hv; hv.x = h0; hv.y = h1;
      *(float2*)(Yd + ((size_t)(br0 + er) * T_ + (s + 1)) * H_ + hcg) = hv;
    }
  }
}

// ---------------------------------------------------------------------------
// Phase 2: GEMM (M=BT, N=512, K=512), 128x128 tile, BK=64, 4 waves (2x2).
// MODE 0: A = Y fp32 (d_out); epi: Abf = bf16(tanh(acc + b1 + s*w1s))
// MODE 1: A = Abf bf16;       epi: Yd += dt * t[row] * (acc + b2)
// ---------------------------------------------------------------------------
template <int MODE>
__launch_bounds__(256)
__global__ void ode_gemm(const void* __restrict__ Asrc,
                         const u16* __restrict__ Wbf,
                         const float* __restrict__ bias,
                         const float* __restrict__ aux,   // MODE0: w1s ; MODE1: t (BT)
                         float* __restrict__ Yd,
                         u16* __restrict__ Abf_out,
                         float sval) {                    // MODE0: s ; MODE1: dt
  __shared__ u16 As[128][72];
  __shared__ u16 Bs[128][72];

  const int tid  = threadIdx.x;
  const int lane = tid & 63;
  const int wid  = tid >> 6;
  const int wm   = wid >> 1, wn = wid & 1;
  const int n0   = blockIdx.x * 128;
  const size_t m0 = (size_t)blockIdx.y * 128;

  f32x4 acc[4][4] = {};

  const int srow = tid >> 1;           // 0..127
  const int sc0  = (tid & 1) * 32;     // 0 / 32

  for (int kc = 0; kc < 8; ++kc) {
    const int k0 = kc * 64;
    if (MODE == 0) {
      const float4* s4 = (const float4*)((const float*)Asrc + (m0 + srow) * 512 + k0 + sc0);
      for (int u = 0; u < 4; ++u) {
        float4 fa = s4[2 * u], fb = s4[2 * u + 1];
        *(u16x8*)&As[srow][sc0 + u * 8] = pack8(fa, fb);
      }
    } else {
      const u16* s = (const u16*)Asrc + (m0 + srow) * 512 + k0 + sc0;
      for (int u = 0; u < 4; ++u)
        *(u16x8*)&As[srow][sc0 + u * 8] = *(const u16x8*)(s + u * 8);
    }
    {
      const u16* s = Wbf + (size_t)(n0 + srow) * 512 + k0 + sc0;
      for (int u = 0; u < 4; ++u)
        *(u16x8*)&Bs[srow][sc0 + u * 8] = *(const u16x8*)(s + u * 8);
    }
    __syncthreads();

    for (int ks = 0; ks < 2; ++ks) {
      const int kl = ks * 32 + ((lane >> 4) << 3);
      bf16x8 af[4], bfv[4];
      for (int mt = 0; mt < 4; ++mt)
        af[mt] = *(const bf16x8*)&As[wm * 64 + mt * 16 + (lane & 15)][kl];
      for (int nt = 0; nt < 4; ++nt)
        bfv[nt] = *(const bf16x8*)&Bs[wn * 64 + nt * 16 + (lane & 15)][kl];
      for (int mt = 0; mt < 4; ++mt)
        for (int nt = 0; nt < 4; ++nt)
          acc[mt][nt] = __builtin_amdgcn_mfma_f32_16x16x32_bf16(af[mt], bfv[nt], acc[mt][nt], 0, 0, 0);
    }
    __syncthreads();
  }

  for (int mt = 0; mt < 4; ++mt) {
    for (int nt = 0; nt < 4; ++nt) {
      const int coll = wn * 64 + nt * 16 + (lane & 15);
      const int colg = n0 + coll;
      const float bv = bias[colg];
      const float extra = (MODE == 0) ? sval * aux[colg] : 0.f;
      for (int r = 0; r < 4; ++r) {
        const int rowl = wm * 64 + mt * 16 + ((lane >> 4) << 2) + r;
        const size_t rowg = m0 + rowl;
        const float gv = acc[mt][nt][r] + bv + extra;
        if (MODE == 0) {
          Abf_out[rowg * 512 + colg] = f2bf(fast_tanh(gv));
        } else {
          const float tt = aux[rowg];
          Yd[rowg * 512 + colg] = fmaf(sval * tt, gv, Yd[rowg * 512 + colg]);
        }
      }
    }
  }
}

// ---------------------------------------------------------------------------
extern "C" void kernel_launch(void* const* d_in, const int* in_sizes, int n_in,
                              void* d_out, int out_size, void* d_ws, size_t ws_size,
                              hipStream_t stream) {
  const float* x    = (const float*)d_in[0];
  const float* t    = (const float*)d_in[1];
  const float* W_ih = (const float*)d_in[2];
  const float* W_hh = (const float*)d_in[3];
  const float* b_ih = (const float*)d_in[4];
  const float* b_hh = (const float*)d_in[5];
  const float* w1   = (const float*)d_in[6];
  const float* b1   = (const float*)d_in[7];
  const float* w2   = (const float*)d_in[8];
  const float* b2   = (const float*)d_in[9];
  float* Yd = (float*)d_out;   // (B,T,H) fp32; h history and ODE state

  char* ws = (char*)d_ws;
  size_t off = 0;
  auto alloc = [&](size_t bytes) {
    void* p = ws + off;
    off += (bytes + 255) & ~(size_t)255;
    return p;
  };
  u16*      Whh_bf = (u16*)alloc((size_t)G4_ * H_ * 2);          //   2 MB
  u16*      Wih_bf = (u16*)alloc((size_t)G4_ * D_ * 2);          // 512 KB
  u16*      w1y_bf = (u16*)alloc((size_t)H_ * H_ * 2);           // 512 KB
  u16*      w2_bf  = (u16*)alloc((size_t)H_ * H_ * 2);           // 512 KB
  float*    w1s    = (float*)alloc(H_ * 4);
  float*    bsum   = (float*)alloc(G4_ * 4);
  uint32_t* xch    = (uint32_t*)alloc((size_t)2 * B_ * H_ * 4);  // 1 MB
  u16*      Abf    = (u16*)alloc((size_t)BT_ * H_ * 2);          // 256 MB

  prep_kernel<<<4096, 256, 0, stream>>>(W_hh, W_ih, w1, w2, b_ih, b_hh,
                                        Whh_bf, Wih_bf, w1y_bf, w2_bf, w1s, bsum, xch, Yd);

  // Phase 1: persistent LSTM (64 WGs, always co-resident on 256 CUs)
  lstm_persist_kernel<<<dim3(GRP_ * WPG_), 1024, 0, stream>>>(x, Whh_bf, Wih_bf, bsum, Yd, xch);

  // Phase 2: 4 Euler steps, each = two fused GEMMs over all B*T rows
  for (int k = 0; k < 4; ++k) {
    ode_gemm<0><<<dim3(4, 2048), 256, 0, stream>>>(Yd, w1y_bf, b1, w1s, nullptr, Abf, 0.25f * k);
    ode_gemm<1><<<dim3(4, 2048), 256, 0, stream>>>(Abf, w2_bf, b2, t, Yd, nullptr, 0.25f);
  }
}

// Round 4
// 8714.528 us; speedup vs baseline: 1.5815x; 1.5053x over previous
//
#include <hip/hip_runtime.h>
#include <stdint.h>

// Problem dims (fixed)
#define B_  256
#define T_  1024
#define D_  128
#define H_  512
#define G4_ 2048            // 4*H
#define BT_ (B_ * T_)

// Persistent-LSTM partitioning
#define GRP_    8           // batch groups (32 rows each)
#define WPG_    8           // workgroups per group (64 hidden cols each)

typedef unsigned short u16;
typedef __attribute__((ext_vector_type(8))) short    bf16x8;  // 8 bf16 in 4 VGPRs
typedef __attribute__((ext_vector_type(8))) u16      u16x8;
typedef __attribute__((ext_vector_type(4))) u16      u16x4;
typedef __attribute__((ext_vector_type(4))) float    f32x4;
typedef __attribute__((ext_vector_type(4))) uint32_t u32x4;

static __device__ __forceinline__ u16 f2bf(float f) {
  uint32_t u = __builtin_bit_cast(uint32_t, f);
  u += 0x7FFFu + ((u >> 16) & 1u);   // RNE
  return (u16)(u >> 16);
}

static __device__ __forceinline__ u16x8 pack8(float4 a, float4 b) {
  u16x8 p;
  p[0] = f2bf(a.x); p[1] = f2bf(a.y); p[2] = f2bf(a.z); p[3] = f2bf(a.w);
  p[4] = f2bf(b.x); p[5] = f2bf(b.y); p[6] = f2bf(b.z); p[7] = f2bf(b.w);
  return p;
}

static __device__ __forceinline__ float fast_sig(float x) {
  return 1.f / (1.f + __expf(-x));
}
static __device__ __forceinline__ float fast_tanh(float x) {
  return 1.f - 2.f / (__expf(2.f * x) + 1.f);
}

// ---------------------------------------------------------------------------
// prep: bf16 weight copies, bias sum, zero exchange buffer and out[:,0,:]
// ---------------------------------------------------------------------------
__global__ void prep_kernel(const float* __restrict__ Whh, const float* __restrict__ Wih,
                            const float* __restrict__ w1,  const float* __restrict__ w2,
                            const float* __restrict__ b_ih, const float* __restrict__ b_hh,
                            u16* __restrict__ Whh_bf, u16* __restrict__ Wih_bf,
                            u16* __restrict__ w1y_bf, u16* __restrict__ w2_bf,
                            float* __restrict__ w1s, float* __restrict__ bsum,
                            uint32_t* __restrict__ xch, float* __restrict__ Yd) {
  const int idx = blockIdx.x * blockDim.x + threadIdx.x;
  if (idx < G4_ * H_) Whh_bf[idx] = f2bf(Whh[idx]);          // 1,048,576
  if (idx < G4_ * D_) Wih_bf[idx] = f2bf(Wih[idx]);          // 262,144
  if (idx < H_ * H_) {                                       // 262,144
    const int n = idx >> 9, k = idx & 511;
    w1y_bf[idx] = f2bf(w1[n * 513 + 1 + k]);                 // w1[:,1:]
    w2_bf[idx]  = f2bf(w2[idx]);
  }
  if (idx < H_)  w1s[idx]  = w1[idx * 513];                  // w1[:,0]
  if (idx < G4_) bsum[idx] = b_ih[idx] + b_hh[idx];
  if (idx < 2 * B_ * H_) xch[idx] = 0;                       // 262,144 (tag 0)
  if (idx < B_ * H_) {                                       // 131,072
    const int b = idx >> 9, h = idx & 511;
    Yd[(size_t)b * T_ * H_ + h] = 0.f;                       // out[b,0,:] = h_0 = 0
  }
}

// ---------------------------------------------------------------------------
// Phase 1: persistent LSTM. Grid = 64 WGs x 1024 thr (16 waves).
// WG (g, j): batch rows [g*32, g*32+32), hidden cols [j*64, j*64+64).
// Weights in VGPRs (20 bf16x8 frags/lane); c-state in 2 regs/thread.
//
// Cross-WG h exchange: self-validating tagged u32 words ((bf16<<16)|step),
// raster layout row*512+col. Producer stores u64 pairs (relaxed agent atomic,
// MALL write-through). Consumers poll with COALESCED inline-asm
// global_load_dwordx4 sc0 sc1 (thread t reads 16B at i*16KB + t*16 -> each
// wave instruction covers 1KB contiguous; 100% line efficiency at the MALL).
// Double-buffered by step parity; overwrite of parity p is gated by having
// observed all tags of the following step (every peer already consumed p).
// ---------------------------------------------------------------------------
__launch_bounds__(1024, 4)
__global__ void lstm_persist_kernel(const float* __restrict__ x,
                                    const u16* __restrict__ Whh_bf,
                                    const u16* __restrict__ Wih_bf,
                                    const float* __restrict__ bsum,
                                    float* __restrict__ Yd,
                                    uint32_t* __restrict__ xch) {
  __shared__ u16   As[32][648];       // 32 x 640 bf16 A-tile
  __shared__ float Gs[4][32][66];     // gate exchange

  const int tid  = threadIdx.x;
  const int lane = tid & 63;
  const int wv   = tid >> 6;          // 0..15
  const int gw   = wv & 3;            // gate (i,f,g,o)
  const int hb   = wv >> 2;           // hidden block 0..3
  const int g    = blockIdx.x >> 3;   // batch group
  const int j    = blockIdx.x & 7;    // col group
  const int br0  = g * 32;
  const int hc0  = j * 64;

  // ---- persistent weight fragments (80 VGPR/lane) ----
  bf16x8 wfrag[20];
  {
    const int jj = gw * H_ + hc0 + hb * 16 + (lane & 15);
    const int ko = (lane >> 4) * 8;
#pragma unroll
    for (int kt = 0; kt < 16; ++kt)
      wfrag[kt] = *(const bf16x8*)(Whh_bf + (size_t)jj * H_ + kt * 32 + ko);
#pragma unroll
    for (int kt = 0; kt < 4; ++kt)
      wfrag[16 + kt] = *(const bf16x8*)(Wih_bf + (size_t)jj * D_ + kt * 32 + ko);
  }

  // ---- per-thread cell state: row er, cols (hcg, hcg+1) ----
  const int er  = tid >> 5;           // 0..31
  const int ec  = (tid & 31) * 2;     // 0..62 (even)
  const int hcg = hc0 + ec;
  float c0 = 0.f, c1 = 0.f;
  const float bi0 = bsum[hcg],            bi1 = bsum[hcg + 1];
  const float bf0 = bsum[H_ + hcg],       bf1 = bsum[H_ + hcg + 1];
  const float bg0 = bsum[2 * H_ + hcg],   bg1 = bsum[2 * H_ + hcg + 1];
  const float bo0 = bsum[3 * H_ + hcg],   bo1 = bsum[3 * H_ + hcg + 1];

  // staging maps
  const int sr  = tid & 31;           // x-stage row
  const int sk  = tid >> 5;           // x-stage chunk
  const int pc  = (tid * 4) & 511;    // poll col (u32 words)
  const int pr0 = tid >> 7;           // poll base row 0..7

  for (int s = 0; s < T_ - 1; ++s) {
    // ---- stage x-part (cols 512..639) — independent of h_s ----
    if (tid < 512) {
      const float4* x4 = (const float4*)(x + ((size_t)(br0 + sr) * T_ + s) * D_);
      float4 a = x4[2 * sk], b = x4[2 * sk + 1];
      *(u16x8*)&As[sr][(sk + 64) * 8] = pack8(a, b);
    }

    // ---- stage h-part (cols 0..511): coalesced tagged poll ----
    if (s == 0) {
      u16x4 z = {};
      *(u16x4*)&As[pr0][pc]      = z;
      *(u16x4*)&As[pr0 + 8][pc]  = z;
      *(u16x4*)&As[pr0 + 16][pc] = z;
      *(u16x4*)&As[pr0 + 24][pc] = z;
    } else {
      const char* base = (const char*)(xch + ((size_t)(s & 1) * B_ + br0) * H_);
      const char* p0 = base + tid * 16;
      const char* p1 = p0 + 16384;
      const char* p2 = p0 + 32768;
      const char* p3 = p0 + 49152;
      const uint32_t want = (uint32_t)s;
      u32x4 r0, r1, r2, r3;
      bool ok;
      do {
        asm volatile(
          "global_load_dwordx4 %0, %4, off sc0 sc1\n\t"
          "global_load_dwordx4 %1, %5, off sc0 sc1\n\t"
          "global_load_dwordx4 %2, %6, off sc0 sc1\n\t"
          "global_load_dwordx4 %3, %7, off sc0 sc1\n\t"
          "s_waitcnt vmcnt(0)"
          : "=&v"(r0), "=&v"(r1), "=&v"(r2), "=&v"(r3)
          : "v"(p0), "v"(p1), "v"(p2), "v"(p3)
          : "memory");
        ok = true;
#pragma unroll
        for (int i = 0; i < 4; ++i) {
          ok = ok && ((r0[i] & 0xFFFFu) == want) && ((r1[i] & 0xFFFFu) == want)
                  && ((r2[i] & 0xFFFFu) == want) && ((r3[i] & 0xFFFFu) == want);
        }
      } while (!ok);
      u16x4 d0, d1, d2, d3;
#pragma unroll
      for (int i = 0; i < 4; ++i) {
        d0[i] = (u16)(r0[i] >> 16);
        d1[i] = (u16)(r1[i] >> 16);
        d2[i] = (u16)(r2[i] >> 16);
        d3[i] = (u16)(r3[i] >> 16);
      }
      *(u16x4*)&As[pr0][pc]      = d0;
      *(u16x4*)&As[pr0 + 8][pc]  = d1;
      *(u16x4*)&As[pr0 + 16][pc] = d2;
      *(u16x4*)&As[pr0 + 24][pc] = d3;
    }
    __syncthreads();

    // ---- MFMA: 2 M-tiles x 1 N-tile x K=640 ----
    f32x4 acc0 = {}, acc1 = {};
    {
      const int ar = lane & 15;
      const int ko = (lane >> 4) * 8;
#pragma unroll
      for (int kt = 0; kt < 20; ++kt) {
        bf16x8 a0 = *(const bf16x8*)&As[ar][kt * 32 + ko];
        bf16x8 a1 = *(const bf16x8*)&As[16 + ar][kt * 32 + ko];
        acc0 = __builtin_amdgcn_mfma_f32_16x16x32_bf16(a0, wfrag[kt], acc0, 0, 0, 0);
        acc1 = __builtin_amdgcn_mfma_f32_16x16x32_bf16(a1, wfrag[kt], acc1, 0, 0, 0);
      }
    }

    // ---- gate exchange ----
    {
      const int gc = hb * 16 + (lane & 15);
      const int rr = (lane >> 4) * 4;
#pragma unroll
      for (int r = 0; r < 4; ++r) {
        Gs[gw][rr + r][gc]      = acc0[r];
        Gs[gw][16 + rr + r][gc] = acc1[r];
      }
    }
    __syncthreads();

    // ---- cell update + h publication ----
    {
      const float gi0 = Gs[0][er][ec] + bi0, gi1 = Gs[0][er][ec + 1] + bi1;
      const float gf0 = Gs[1][er][ec] + bf0, gf1 = Gs[1][er][ec + 1] + bf1;
      const float gg0 = Gs[2][er][ec] + bg0, gg1 = Gs[2][er][ec + 1] + bg1;
      const float go0 = Gs[3][er][ec] + bo0, go1 = Gs[3][er][ec + 1] + bo1;
      c0 = fast_sig(gf0) * c0 + fast_sig(gi0) * fast_tanh(gg0);
      c1 = fast_sig(gf1) * c1 + fast_sig(gi1) * fast_tanh(gg1);
      const float h0 = fast_sig(go0) * fast_tanh(c0);
      const float h1 = fast_sig(go1) * fast_tanh(c1);
      const uint32_t tag = (uint32_t)(s + 1);
      const uint32_t lo  = ((uint32_t)f2bf(h0) << 16) | tag;
      const uint32_t hi  = ((uint32_t)f2bf(h1) << 16) | tag;
      // tagged bf16 exchange word first (consumers wait on it) ...
      __hip_atomic_store((uint64_t*)(xch + (((size_t)((s + 1) & 1) * B_ + br0 + er) << 9) + hcg),
                         ((uint64_t)hi << 32) | lo,
                         __ATOMIC_RELAXED, __HIP_MEMORY_SCOPE_AGENT);
      // ... then the fp32 history for phase 2 / output
      float2 hv; hv.x = h0; hv.y = h1;
      *(float2*)(Yd + ((size_t)(br0 + er) * T_ + (s + 1)) * H_ + hcg) = hv;
    }
  }
}

// ---------------------------------------------------------------------------
// Phase 2 (fused): all 4 Euler steps in one kernel.
// WG = 512 thr (8 waves as 2x4), tile = 64 rows x 512 cols, grid 4096.
// Y held fp32 in registers across steps. A-tile (bf16 of Y or G1) in LDS.
// w1/w2 streamed through double-buffered LDS B-chunks (K=32 each).
// ---------------------------------------------------------------------------
static __device__ __forceinline__ void gemm512(const u16* __restrict__ W,
                                               u16 (*At)[520], u16 (*Bs)[512][40],
                                               f32x4 acc[2][8],
                                               int tid, int wr, int wc, int lane) {
  const int cl = lane & 15;
  const int kq = (lane >> 4) * 8;     // k offset within 32-chunk (u16 units)
  // stage chunk 0
  {
    const uint4* g4 = (const uint4*)(W + (size_t)tid * 512);
    uint4 v0 = g4[0], v1 = g4[1], v2 = g4[2], v3 = g4[3];
    *(uint4*)&Bs[0][tid][0]  = v0;
    *(uint4*)&Bs[0][tid][8]  = v1;
    *(uint4*)&Bs[0][tid][16] = v2;
    *(uint4*)&Bs[0][tid][24] = v3;
  }
  __syncthreads();
#pragma unroll 2
  for (int c = 0; c < 16; ++c) {
    uint4 p0, p1, p2, p3;
    if (c < 15) {
      const uint4* g4 = (const uint4*)(W + (size_t)tid * 512 + (c + 1) * 32);
      p0 = g4[0]; p1 = g4[1]; p2 = g4[2]; p3 = g4[3];
    }
    bf16x8 af[2];
#pragma unroll
    for (int mt = 0; mt < 2; ++mt)
      af[mt] = *(const bf16x8*)&At[wr * 32 + mt * 16 + cl][c * 32 + kq];
#pragma unroll
    for (int nt = 0; nt < 8; ++nt) {
      bf16x8 bfv = *(const bf16x8*)&Bs[c & 1][wc * 128 + nt * 16 + cl][kq];
      acc[0][nt] = __builtin_amdgcn_mfma_f32_16x16x32_bf16(af[0], bfv, acc[0][nt], 0, 0, 0);
      acc[1][nt] = __builtin_amdgcn_mfma_f32_16x16x32_bf16(af[1], bfv, acc[1][nt], 0, 0, 0);
    }
    if (c < 15) {
      *(uint4*)&Bs[(c + 1) & 1][tid][0]  = p0;
      *(uint4*)&Bs[(c + 1) & 1][tid][8]  = p1;
      *(uint4*)&Bs[(c + 1) & 1][tid][16] = p2;
      *(uint4*)&Bs[(c + 1) & 1][tid][24] = p3;
    }
    __syncthreads();
  }
}

__launch_bounds__(512)
__global__ void ode_fused(const float* __restrict__ tptr,
                          const u16* __restrict__ w1y,
                          const u16* __restrict__ w2v,
                          const float* __restrict__ b1,
                          const float* __restrict__ b2,
                          const float* __restrict__ w1s,
                          float* __restrict__ Yd) {
  __shared__ u16 At[64][520];         // 66.6 KB
  __shared__ u16 Bs[2][512][40];      // 80 KB (double-buffered K=32 chunks)

  const int tid  = threadIdx.x;
  const int lane = tid & 63;
  const int wv   = tid >> 6;          // 0..7
  const int wr   = wv >> 2;           // 0..1 (rows wr*32)
  const int wc   = wv & 3;            // 0..3 (cols wc*128)
  const size_t m0 = (size_t)blockIdx.x * 64;

  const int rq = (lane >> 4) * 4;
  const int cl = lane & 15;
  const int rbase = wr * 32;
  const int cbase = wc * 128;

  // biases / w1s per n-tile
  float b1v[8], b2v[8], w1sv[8];
#pragma unroll
  for (int nt = 0; nt < 8; ++nt) {
    const int c = cbase + nt * 16 + cl;
    b1v[nt] = b1[c]; b2v[nt] = b2[c]; w1sv[nt] = w1s[c];
  }
  // dt*t per (mt, r) row
  float tv[2][4];
#pragma unroll
  for (int mt = 0; mt < 2; ++mt)
#pragma unroll
    for (int r = 0; r < 4; ++r)
      tv[mt][r] = 0.25f * tptr[m0 + rbase + mt * 16 + rq + r];

  // load Y (fp32) into registers (MFMA C layout)
  f32x4 Y[2][8];
#pragma unroll
  for (int mt = 0; mt < 2; ++mt)
#pragma unroll
    for (int nt = 0; nt < 8; ++nt)
#pragma unroll
      for (int r = 0; r < 4; ++r)
        Y[mt][nt][r] = Yd[(m0 + rbase + mt * 16 + rq + r) * 512 + cbase + nt * 16 + cl];

#define WRITE_AT(EXPR)                                                        \
  do {                                                                        \
    _Pragma("unroll") for (int mt = 0; mt < 2; ++mt)                          \
    _Pragma("unroll") for (int nt = 0; nt < 8; ++nt)                          \
    _Pragma("unroll") for (int r = 0; r < 4; ++r)                             \
      At[rbase + mt * 16 + rq + r][cbase + nt * 16 + cl] = f2bf(EXPR);        \
  } while (0)

  // initial A-tile = bf16(Y)   (At not yet read by anyone; barrier inside gemm)
  WRITE_AT(Y[mt][nt][r]);

#pragma unroll
  for (int k = 0; k < 4; ++k) {
    const float sk = 0.25f * k;
    // ---- GEMM1: G1 = tanh(A @ w1y^T + b1 + s*w1s) ----
    f32x4 acc1[2][8] = {};
    gemm512(w1y, At, Bs, acc1, tid, wr, wc, lane);
    // all waves past final barrier -> At reads done; safe to overwrite
    WRITE_AT(fast_tanh(acc1[mt][nt][r] + b1v[nt] + sk * w1sv[nt]));
    __syncthreads();
    // ---- GEMM2: Y += dt*t*(G1 @ w2^T + b2) ----
    f32x4 acc2[2][8] = {};
    gemm512(w2v, At, Bs, acc2, tid, wr, wc, lane);
#pragma unroll
    for (int mt = 0; mt < 2; ++mt)
#pragma unroll
      for (int nt = 0; nt < 8; ++nt)
#pragma unroll
        for (int r = 0; r < 4; ++r)
          Y[mt][nt][r] += tv[mt][r] * (acc2[mt][nt][r] + b2v[nt]);
    if (k < 3) {
      WRITE_AT(Y[mt][nt][r]);       // next step's A-tile
      __syncthreads();
    }
  }
#undef WRITE_AT

  // write back Y (fp32)
#pragma unroll
  for (int mt = 0; mt < 2; ++mt)
#pragma unroll
    for (int nt = 0; nt < 8; ++nt)
#pragma unroll
      for (int r = 0; r < 4; ++r)
        Yd[(m0 + rbase + mt * 16 + rq + r) * 512 + cbase + nt * 16 + cl] = Y[mt][nt][r];
}

// ---------------------------------------------------------------------------
extern "C" void kernel_launch(void* const* d_in, const int* in_sizes, int n_in,
                              void* d_out, int out_size, void* d_ws, size_t ws_size,
                              hipStream_t stream) {
  const float* x    = (const float*)d_in[0];
  const float* t    = (const float*)d_in[1];
  const float* W_ih = (const float*)d_in[2];
  const float* W_hh = (const float*)d_in[3];
  const float* b_ih = (const float*)d_in[4];
  const float* b_hh = (const float*)d_in[5];
  const float* w1   = (const float*)d_in[6];
  const float* b1   = (const float*)d_in[7];
  const float* w2   = (const float*)d_in[8];
  const float* b2   = (const float*)d_in[9];
  float* Yd = (float*)d_out;   // (B,T,H) fp32; h history and ODE state

  char* ws = (char*)d_ws;
  size_t off = 0;
  auto alloc = [&](size_t bytes) {
    void* p = ws + off;
    off += (bytes + 255) & ~(size_t)255;
    return p;
  };
  u16*      Whh_bf = (u16*)alloc((size_t)G4_ * H_ * 2);          //   2 MB
  u16*      Wih_bf = (u16*)alloc((size_t)G4_ * D_ * 2);          // 512 KB
  u16*      w1y_bf = (u16*)alloc((size_t)H_ * H_ * 2);           // 512 KB
  u16*      w2_bf  = (u16*)alloc((size_t)H_ * H_ * 2);           // 512 KB
  float*    w1s    = (float*)alloc(H_ * 4);
  float*    bsum   = (float*)alloc(G4_ * 4);
  uint32_t* xch    = (uint32_t*)alloc((size_t)2 * B_ * H_ * 4);  // 1 MB

  prep_kernel<<<4096, 256, 0, stream>>>(W_hh, W_ih, w1, w2, b_ih, b_hh,
                                        Whh_bf, Wih_bf, w1y_bf, w2_bf, w1s, bsum, xch, Yd);

  // Phase 1: persistent LSTM (64 WGs, always co-resident on 256 CUs)
  lstm_persist_kernel<<<dim3(GRP_ * WPG_), 1024, 0, stream>>>(x, Whh_bf, Wih_bf, bsum, Yd, xch);

  // Phase 2: fused 4-step Euler ODE over all B*T rows
  ode_fused<<<dim3(BT_ / 64), 512, 0, stream>>>(t, w1y_bf, w2_bf, b1, b2, w1s, Yd);
}

// Round 5
// 7028.310 us; speedup vs baseline: 1.9609x; 1.2399x over previous
//
#include <hip/hip_runtime.h>
#include <stdint.h>

// Problem dims (fixed)
#define B_  256
#define T_  1024
#define D_  128
#define H_  512
#define G4_ 2048            // 4*H
#define BT_ (B_ * T_)

// Persistent-LSTM partitioning: 16 batch groups x 16 col groups = 256 WGs
#define NG_ 16              // batch groups (16 rows each)
#define NC_ 16              // col groups (32 h-cols each)

typedef unsigned short u16;
typedef __attribute__((ext_vector_type(8))) short    bf16x8;  // 8 bf16 in 4 VGPRs
typedef __attribute__((ext_vector_type(8))) u16      u16x8;
typedef __attribute__((ext_vector_type(4))) float    f32x4;
typedef __attribute__((ext_vector_type(4))) uint32_t u32x4;

static __device__ __forceinline__ u16 f2bf(float f) {
  uint32_t u = __builtin_bit_cast(uint32_t, f);
  u += 0x7FFFu + ((u >> 16) & 1u);   // RNE
  return (u16)(u >> 16);
}

static __device__ __forceinline__ u16x8 pack8(float4 a, float4 b) {
  u16x8 p;
  p[0] = f2bf(a.x); p[1] = f2bf(a.y); p[2] = f2bf(a.z); p[3] = f2bf(a.w);
  p[4] = f2bf(b.x); p[5] = f2bf(b.y); p[6] = f2bf(b.z); p[7] = f2bf(b.w);
  return p;
}

static __device__ __forceinline__ float fast_sig(float x) {
  return 1.f / (1.f + __expf(-x));
}
static __device__ __forceinline__ float fast_tanh(float x) {
  return 1.f - 2.f / (__expf(2.f * x) + 1.f);
}

// ---------------------------------------------------------------------------
// prep: bf16 weight copies, bias sum, zero flag buffer and out[:,0,:]
// ---------------------------------------------------------------------------
__global__ void prep_kernel(const float* __restrict__ Whh, const float* __restrict__ Wih,
                            const float* __restrict__ w1,  const float* __restrict__ w2,
                            const float* __restrict__ b_ih, const float* __restrict__ b_hh,
                            u16* __restrict__ Whh_bf, u16* __restrict__ Wih_bf,
                            u16* __restrict__ w1y_bf, u16* __restrict__ w2_bf,
                            float* __restrict__ w1s, float* __restrict__ bsum,
                            uint32_t* __restrict__ flags, float* __restrict__ Yd) {
  const int idx = blockIdx.x * blockDim.x + threadIdx.x;
  if (idx < G4_ * H_) Whh_bf[idx] = f2bf(Whh[idx]);          // 1,048,576
  if (idx < G4_ * D_) Wih_bf[idx] = f2bf(Wih[idx]);          // 262,144
  if (idx < H_ * H_) {                                       // 262,144
    const int n = idx >> 9, k = idx & 511;
    w1y_bf[idx] = f2bf(w1[n * 513 + 1 + k]);                 // w1[:,1:]
    w2_bf[idx]  = f2bf(w2[idx]);
  }
  if (idx < H_)  w1s[idx]  = w1[idx * 513];                  // w1[:,0]
  if (idx < G4_) bsum[idx] = b_ih[idx] + b_hh[idx];
  if (idx < T_ * NG_ * 4) flags[idx] = 0;                    // 65,536 u32 = 256 KB
  if (idx < B_ * H_) {                                       // 131,072
    const int b = idx >> 9, h = idx & 511;
    Yd[(size_t)b * T_ * H_ + h] = 0.f;                       // out[b,0,:] = h_0 = 0
  }
}

// ---------------------------------------------------------------------------
// Phase 1: persistent LSTM v3. Grid = 256 WGs x 256 thr (4 waves).
// WG (g,c): rows [g*16,+16), h-cols [c*32,+32). Wave gw = one gate; its
// 128x640 weight slice lives in 160 VGPR/lane (wf0/wf1 = 2 n-frags x 20 kt).
//
// Exchange: producers store untagged bf16 h pairs (sc0 sc1 -> MALL), drain
// vmcnt(0), barrier, then tid0 stores a byte flag (16 producer flags packed
// in one 16B word per (step,group)). Consumers poll that single dwordx4
// (broadcast-merged), then bulk-read 64 B/thread once. Release = store-ack
// (vmcnt) before flag; flags are per-step buffers (no reuse), zeroed by prep.
// Group<->XCD affinity via g=(w&7)*2+(w>>7) keeps x 16x-reuse L2-local
// (perf-only; correctness is placement-independent through the MALL).
// ---------------------------------------------------------------------------
__launch_bounds__(256)
__global__ void lstm_persist2(const float* __restrict__ x,
                              const u16* __restrict__ Whh_bf,
                              const u16* __restrict__ Wih_bf,
                              const float* __restrict__ bsum,
                              float* __restrict__ Yd,
                              u16* __restrict__ xchh,
                              uint32_t* __restrict__ flags) {
  __shared__ u16   As[16][648];       // 16 x 640 bf16 A-tile (+pad)
  __shared__ float Gs[4][16][34];     // gate exchange

  const int tid  = threadIdx.x;
  const int lane = tid & 63;
  const int gw   = tid >> 6;          // gate 0..3
  const int w    = blockIdx.x;
  const int g    = (w & 7) * 2 + (w >> 7);   // batch group (XCD-affine)
  const int c    = (w >> 3) & 15;            // col group
  const int br0  = g * 16;
  const int hc0  = c * 32;

  const int cl = lane & 15;
  const int ko = (lane >> 4) * 8;

  // ---- persistent weight fragments: gate gw, cols hc0..hc0+32 ----
  bf16x8 wf0[20], wf1[20];
  {
    const int j0 = gw * H_ + hc0 + cl;
#pragma unroll
    for (int kt = 0; kt < 16; ++kt) {
      wf0[kt] = *(const bf16x8*)(Whh_bf + (size_t)j0 * H_ + kt * 32 + ko);
      wf1[kt] = *(const bf16x8*)(Whh_bf + (size_t)(j0 + 16) * H_ + kt * 32 + ko);
    }
#pragma unroll
    for (int kt = 0; kt < 4; ++kt) {
      wf0[16 + kt] = *(const bf16x8*)(Wih_bf + (size_t)j0 * D_ + kt * 32 + ko);
      wf1[16 + kt] = *(const bf16x8*)(Wih_bf + (size_t)(j0 + 16) * D_ + kt * 32 + ko);
    }
  }

  // ---- per-thread cell state: row er, cols (jb, jb+1) ----
  const int er = tid >> 4;            // 0..15
  const int ec = (tid & 15) * 2;      // 0..30
  const int jb = hc0 + ec;
  float c0 = 0.f, c1 = 0.f;
  const float bi0 = bsum[jb],            bi1 = bsum[jb + 1];
  const float bf0 = bsum[H_ + jb],       bf1 = bsum[H_ + jb + 1];
  const float bg0 = bsum[2 * H_ + jb],   bg1 = bsum[2 * H_ + jb + 1];
  const float bo0 = bsum[3 * H_ + jb],   bo1 = bsum[3 * H_ + jb + 1];

  const int xr  = tid & 15,  xk  = tid >> 4;   // x-stage map
  const int pr  = tid >> 4,  pcb = tid & 15;   // bulk-read map

  for (int s = 0; s < T_ - 1; ++s) {
    // ---- stage x-part (cols 512..639) — independent of h_s ----
    {
      const float4* x4 = (const float4*)(x + ((size_t)(br0 + xr) * T_ + s) * D_ + xk * 8);
      float4 a = x4[0], b = x4[1];
      *(u16x8*)&As[xr][512 + xk * 8] = pack8(a, b);
    }

    // ---- stage h-part (cols 0..511) ----
    if (s == 0) {
      u16x8 z = {};
#pragma unroll
      for (int i = 0; i < 4; ++i) *(u16x8*)&As[pr][pcb * 32 + i * 8] = z;
    } else {
      // poll the 16 packed producer flags (one dwordx4)
      const char* fp = (const char*)flags + ((size_t)s * NG_ + g) * 16;
      u32x4 f;
      do {
        asm volatile("global_load_dwordx4 %0, %1, off sc0 sc1\n\ts_waitcnt vmcnt(0)"
                     : "=&v"(f) : "v"(fp) : "memory");
      } while (f[0] != 0xA5A5A5A5u || f[1] != 0xA5A5A5A5u ||
               f[2] != 0xA5A5A5A5u || f[3] != 0xA5A5A5A5u);
      // bulk-read 64 B of bf16 h (once)
      const char* hb = (const char*)xchh + (((size_t)(s & 1) * NG_ + g) << 14) + tid * 64;
      u32x4 h0, h1, h2, h3;
      asm volatile(
        "global_load_dwordx4 %0, %4, off sc0 sc1\n\t"
        "global_load_dwordx4 %1, %4, off offset:16 sc0 sc1\n\t"
        "global_load_dwordx4 %2, %4, off offset:32 sc0 sc1\n\t"
        "global_load_dwordx4 %3, %4, off offset:48 sc0 sc1\n\t"
        "s_waitcnt vmcnt(0)"
        : "=&v"(h0), "=&v"(h1), "=&v"(h2), "=&v"(h3)
        : "v"(hb) : "memory");
      *(u16x8*)&As[pr][pcb * 32]      = __builtin_bit_cast(u16x8, h0);
      *(u16x8*)&As[pr][pcb * 32 + 8]  = __builtin_bit_cast(u16x8, h1);
      *(u16x8*)&As[pr][pcb * 32 + 16] = __builtin_bit_cast(u16x8, h2);
      *(u16x8*)&As[pr][pcb * 32 + 24] = __builtin_bit_cast(u16x8, h3);
    }
    __syncthreads();

    // ---- MFMA: M=16, N=32 (2 frags), K=640 ----
    f32x4 acc0 = {}, acc1 = {};
#pragma unroll
    for (int kt = 0; kt < 20; ++kt) {
      bf16x8 a = *(const bf16x8*)&As[cl][kt * 32 + ko];
      acc0 = __builtin_amdgcn_mfma_f32_16x16x32_bf16(a, wf0[kt], acc0, 0, 0, 0);
      acc1 = __builtin_amdgcn_mfma_f32_16x16x32_bf16(a, wf1[kt], acc1, 0, 0, 0);
    }

    // ---- gate exchange ----
    {
      const int rr = (lane >> 4) * 4;
#pragma unroll
      for (int r = 0; r < 4; ++r) {
        Gs[gw][rr + r][cl]      = acc0[r];
        Gs[gw][rr + r][16 + cl] = acc1[r];
      }
    }
    __syncthreads();

    // ---- cell update + h publication ----
    {
      const float2 gi = *(const float2*)&Gs[0][er][ec];
      const float2 gf = *(const float2*)&Gs[1][er][ec];
      const float2 gg = *(const float2*)&Gs[2][er][ec];
      const float2 go = *(const float2*)&Gs[3][er][ec];
      c0 = fast_sig(gf.x + bf0) * c0 + fast_sig(gi.x + bi0) * fast_tanh(gg.x + bg0);
      c1 = fast_sig(gf.y + bf1) * c1 + fast_sig(gi.y + bi1) * fast_tanh(gg.y + bg1);
      const float h0v = fast_sig(go.x + bo0) * fast_tanh(c0);
      const float h1v = fast_sig(go.y + bo1) * fast_tanh(c1);
      const uint32_t hw = ((uint32_t)f2bf(h1v) << 16) | f2bf(h0v);
      u16* dst16 = xchh + ((((size_t)((s + 1) & 1) * NG_ + g) * 16 + er) << 9) + jb;
      asm volatile("global_store_dword %0, %1, off sc0 sc1" :: "v"(dst16), "v"(hw) : "memory");
      float2 hv; hv.x = h0v; hv.y = h1v;
      *(float2*)(Yd + ((size_t)(br0 + er) * T_ + (s + 1)) * H_ + jb) = hv;
      asm volatile("s_waitcnt vmcnt(0)" ::: "memory");
    }
    __syncthreads();   // all threads' publishes acked

    if (tid == 0) {
      const char* fb = (const char*)flags + ((size_t)(s + 1) * NG_ + g) * 16 + c;
      uint32_t pat = 0xA5u;
      asm volatile("global_store_byte %0, %1, off sc0 sc1" :: "v"(fb), "v"(pat) : "memory");
    }
  }
}

// ---------------------------------------------------------------------------
// Phase 2 (fused, v2): all 4 Euler steps; 64 rows x 512 cols per WG.
// 8 waves, 1x8 layout: each wave M=64 (4 m-frags), N=64 (4 n-frags).
// Y fp32 in regs; A-tile (bf16 Y / G1) in LDS; B (weights) loaded DIRECTLY
// from global (512 KB, L2-resident, 100% line efficiency) — no B LDS, no
// double-buffer, 4 barriers/step. LDS 66.5 KB -> 2 WGs/CU overlap.
// ---------------------------------------------------------------------------
__launch_bounds__(512)
__global__ void ode_fused2(const float* __restrict__ tptr,
                           const u16* __restrict__ w1y,
                           const u16* __restrict__ w2v,
                           const float* __restrict__ b1,
                           const float* __restrict__ b2,
                           const float* __restrict__ w1s,
                           float* __restrict__ Yd) {
  __shared__ u16 At[64][520];

  const int tid  = threadIdx.x;
  const int lane = tid & 63;
  const int wv   = tid >> 6;          // 0..7
  const int n0w  = wv * 64;
  const size_t m0 = (size_t)blockIdx.x * 64;
  const int cl = lane & 15;
  const int rq = (lane >> 4) * 4;
  const int ko = (lane >> 4) * 8;

  float b1v[4], b2v[4], w1sv[4];
#pragma unroll
  for (int nf = 0; nf < 4; ++nf) {
    const int cg = n0w + nf * 16 + cl;
    b1v[nf] = b1[cg]; b2v[nf] = b2[cg]; w1sv[nf] = w1s[cg];
  }
  float tv[4][4];
#pragma unroll
  for (int mf = 0; mf < 4; ++mf)
#pragma unroll
    for (int r = 0; r < 4; ++r)
      tv[mf][r] = 0.25f * tptr[m0 + mf * 16 + rq + r];

  // load Y (fp32) into registers (C-frag layout, wave's 64-col band)
  f32x4 Y[4][4];
#pragma unroll
  for (int mf = 0; mf < 4; ++mf)
#pragma unroll
    for (int nf = 0; nf < 4; ++nf)
#pragma unroll
      for (int r = 0; r < 4; ++r)
        Y[mf][nf][r] = Yd[(m0 + mf * 16 + rq + r) * 512 + n0w + nf * 16 + cl];

#define WRITE_AT(EXPR)                                                        \
  do {                                                                        \
    _Pragma("unroll") for (int mf = 0; mf < 4; ++mf)                          \
    _Pragma("unroll") for (int nf = 0; nf < 4; ++nf)                          \
    _Pragma("unroll") for (int r = 0; r < 4; ++r)                             \
      At[mf * 16 + rq + r][n0w + nf * 16 + cl] = f2bf(EXPR);                  \
  } while (0)

#define GEMM_DIRECT(WPTR, ACC)                                                \
  do {                                                                        \
    _Pragma("unroll 2") for (int cc = 0; cc < 16; ++cc) {                     \
      bf16x8 bfv[4], af[4];                                                   \
      _Pragma("unroll") for (int nf = 0; nf < 4; ++nf)                        \
        bfv[nf] = *(const bf16x8*)(WPTR + (size_t)(n0w + nf * 16 + cl) * 512  \
                                   + cc * 32 + ko);                           \
      _Pragma("unroll") for (int mf = 0; mf < 4; ++mf)                        \
        af[mf] = *(const bf16x8*)&At[mf * 16 + cl][cc * 32 + ko];             \
      _Pragma("unroll") for (int mf = 0; mf < 4; ++mf)                        \
      _Pragma("unroll") for (int nf = 0; nf < 4; ++nf)                        \
        ACC[mf][nf] = __builtin_amdgcn_mfma_f32_16x16x32_bf16(                \
            af[mf], bfv[nf], ACC[mf][nf], 0, 0, 0);                           \
    }                                                                         \
  } while (0)

  WRITE_AT(Y[mf][nf][r]);
  __syncthreads();

#pragma unroll
  for (int k = 0; k < 4; ++k) {
    const float sk = 0.25f * k;
    // ---- GEMM1: G1 = tanh(A @ w1y^T + b1 + s*w1s) ----
    f32x4 acc[4][4] = {};
    GEMM_DIRECT(w1y, acc);
    __syncthreads();                  // At reads done
    WRITE_AT(fast_tanh(acc[mf][nf][r] + b1v[nf] + sk * w1sv[nf]));
    __syncthreads();
    // ---- GEMM2: Y += dt*t*(G1 @ w2^T + b2) ----
    f32x4 acc2[4][4] = {};
    GEMM_DIRECT(w2v, acc2);
    __syncthreads();                  // At reads done
#pragma unroll
    for (int mf = 0; mf < 4; ++mf)
#pragma unroll
      for (int nf = 0; nf < 4; ++nf)
#pragma unroll
        for (int r = 0; r < 4; ++r)
          Y[mf][nf][r] += tv[mf][r] * (acc2[mf][nf][r] + b2v[nf]);
    if (k < 3) {
      WRITE_AT(Y[mf][nf][r]);
      __syncthreads();
    }
  }
#undef GEMM_DIRECT
#undef WRITE_AT

  // write back Y (fp32)
#pragma unroll
  for (int mf = 0; mf < 4; ++mf)
#pragma unroll
    for (int nf = 0; nf < 4; ++nf)
#pragma unroll
      for (int r = 0; r < 4; ++r)
        Yd[(m0 + mf * 16 + rq + r) * 512 + n0w + nf * 16 + cl] = Y[mf][nf][r];
}

// ---------------------------------------------------------------------------
extern "C" void kernel_launch(void* const* d_in, const int* in_sizes, int n_in,
                              void* d_out, int out_size, void* d_ws, size_t ws_size,
                              hipStream_t stream) {
  const float* x    = (const float*)d_in[0];
  const float* t    = (const float*)d_in[1];
  const float* W_ih = (const float*)d_in[2];
  const float* W_hh = (const float*)d_in[3];
  const float* b_ih = (const float*)d_in[4];
  const float* b_hh = (const float*)d_in[5];
  const float* w1   = (const float*)d_in[6];
  const float* b1   = (const float*)d_in[7];
  const float* w2   = (const float*)d_in[8];
  const float* b2   = (const float*)d_in[9];
  float* Yd = (float*)d_out;   // (B,T,H) fp32; h history and ODE state

  char* ws = (char*)d_ws;
  size_t off = 0;
  auto alloc = [&](size_t bytes) {
    void* p = ws + off;
    off += (bytes + 255) & ~(size_t)255;
    return p;
  };
  u16*      Whh_bf = (u16*)alloc((size_t)G4_ * H_ * 2);          //   2 MB
  u16*      Wih_bf = (u16*)alloc((size_t)G4_ * D_ * 2);          // 512 KB
  u16*      w1y_bf = (u16*)alloc((size_t)H_ * H_ * 2);           // 512 KB
  u16*      w2_bf  = (u16*)alloc((size_t)H_ * H_ * 2);           // 512 KB
  float*    w1s    = (float*)alloc(H_ * 4);
  float*    bsum   = (float*)alloc(G4_ * 4);
  u16*      xchh   = (u16*)alloc((size_t)2 * NG_ * 16 * H_ * 2); // 512 KB
  uint32_t* flags  = (uint32_t*)alloc((size_t)T_ * NG_ * 16);    // 256 KB

  prep_kernel<<<4096, 256, 0, stream>>>(W_hh, W_ih, w1, w2, b_ih, b_hh,
                                        Whh_bf, Wih_bf, w1y_bf, w2_bf, w1s, bsum, flags, Yd);

  // Phase 1: persistent LSTM (256 WGs x 256 thr; capacity ~5 WGs/CU -> all resident)
  lstm_persist2<<<dim3(NG_ * NC_), 256, 0, stream>>>(x, Whh_bf, Wih_bf, bsum, Yd, xchh, flags);

  // Phase 2: fused 4-step Euler ODE over all B*T rows
  ode_fused2<<<dim3(BT_ / 64), 512, 0, stream>>>(t, w1y_bf, w2_bf, b1, b2, w1s, Yd);
}